// Round 8
// baseline (488.532 us; speedup 1.0000x reference)
//
#include <hip/hip_runtime.h>
#include <hip/hip_bf16.h>

// HierarchicalAttention: B=4,T=50,D=512, SRC=400, SENTS=16, WORDS=40.
// Single cooperative mega-kernel, 5 phases separated by a CUSTOM grid barrier
// (R7 showed cg::grid.sync costs ~100us each on ROCm: all pipes idle, polling
// traffic in FETCH_SIZE). Barrier: one agent-scope atomicAdd per block +
// generation spin on L2-resident counter.
//   A: transposes (weights W->bf16 Wt[n][k]; banks->bf16 Mt[b][d][s])
//   B: MFMA projections (outputs pre-scaled by 2*log2e)
//   C: tanh scores (sigmoid form; masked jobs skipped; 2 waves/job; 13+12 chunks)
//   D: hier combine + mask + softmax -> bf16 P
//   E: MFMA context GEMM (P x M -> out)

#define B_    4
#define T_    50
#define D_    512
#define SRC_  400
#define SENTS_ 16
#define WORDS_ 40
#define NW_   640      // SENTS*WORDS
#define NMEM_ 1040     // SRC + NW
#define NK_   1056     // NMEM padded to 32*33 for MFMA K-loop
#define NJOB_ 1056     // NMEM + SENTS (score jobs per batch)

#define C2L2E 2.8853900817779268f   // 2*log2(e): x -> exp2(C2L2E*x) = exp(2x)

typedef unsigned short ushort_t;
using s8v = __attribute__((ext_vector_type(8))) short;   // 8 bf16 (4 VGPRs)
using f4v = __attribute__((ext_vector_type(4))) float;   // MFMA accumulator

// ---- workspace layout ----
// f32 region (float offsets):
#define OFF_WQ_WORD 0
#define OFF_WQ_SENT 102400
#define OFF_WQ_PASS 204800
#define OFF_UH_SRC  307200
#define OFF_UH_WORD 1126400
#define OFF_UH_SENT 2437120
#define OFF_SC_SRC  2469888
#define OFF_SC_WORD 2549888
#define OFF_SC_SENT 2677888
// f32 region ends at float 2681088 = byte 10724352
// bf16 regions (byte offsets):
#define P_BYTE_OFF  10724352ull   // P[b][64][1056]  bf16 = 540672 B
#define MT_BYTE_OFF 11265024ull   // Mt[b][512][1056] bf16 = 4325376 B
#define WT_BYTE_OFF 15590400ull   // Wt[6][512][512] bf16 = 3145728 B
#define BAR_BYTE_OFF 18736128ull  // 2 ints: {arrive count, generation}

__device__ __forceinline__ ushort_t f2b(float f) {
    __hip_bfloat16 h = __float2bfloat16(f);   // RNE
    return *(ushort_t*)&h;
}

// Sense-reversing grid barrier. All blocks co-resident (cooperative launch).
__device__ __forceinline__ void gbar(int* cnt, int* gen, int nblocks) {
    __syncthreads();
    if (threadIdx.x == 0) {
        __threadfence();   // publish this block's phase writes (agent scope)
        int g = __hip_atomic_load(gen, __ATOMIC_RELAXED, __HIP_MEMORY_SCOPE_AGENT);
        int arrived = __hip_atomic_fetch_add(cnt, 1, __ATOMIC_ACQ_REL,
                                             __HIP_MEMORY_SCOPE_AGENT);
        if (arrived == nblocks - 1) {
            __hip_atomic_store(cnt, 0, __ATOMIC_RELAXED, __HIP_MEMORY_SCOPE_AGENT);
            __hip_atomic_store(gen, g + 1, __ATOMIC_RELEASE, __HIP_MEMORY_SCOPE_AGENT);
        } else {
            while (__hip_atomic_load(gen, __ATOMIC_ACQUIRE,
                                     __HIP_MEMORY_SCOPE_AGENT) == g)
                __builtin_amdgcn_s_sleep(1);
        }
        __threadfence();
    }
    __syncthreads();
}

// Phase-C inner chunk: NT independent t-columns, one butterfly batch.
template<int NT>
__device__ __forceinline__ void score_chunk(
    const float* __restrict__ wqh, int tb, int ostride, int lane,
    const float uhr[8], const float vr[8], float vs,
    float* __restrict__ sco)
{
    int d0 = lane * 8;
    float acc[NT];
#pragma unroll
    for (int u = 0; u < NT; ++u) {
        const float* wr = wqh + (tb + u) * D_ + d0;
        float4 w0 = *(const float4*)(wr);
        float4 w1 = *(const float4*)(wr + 4);
        float wrr[8] = {w0.x, w0.y, w0.z, w0.w, w1.x, w1.y, w1.z, w1.w};
        float a = 0.f;
#pragma unroll
        for (int j = 0; j < 8; ++j) {
            float e = __builtin_amdgcn_exp2f(wrr[j] + uhr[j]);  // exp(2x)
            float r = __builtin_amdgcn_rcpf(e + 1.f);           // sigmoid(-2x)
            a = fmaf(vr[j], r, a);
        }
        acc[u] = a;
    }
#pragma unroll
    for (int off = 32; off > 0; off >>= 1) {
#pragma unroll
        for (int u = 0; u < NT; ++u)
            acc[u] += __shfl_xor(acc[u], off, 64);
    }
    if (lane == 0) {
#pragma unroll
        for (int u = 0; u < NT; ++u)
            sco[(tb + u) * ostride] = fmaf(-2.f, acc[u], vs);
    }
}

__global__ __launch_bounds__(256, 2) void mega(
    const float* __restrict__ source, const float* __restrict__ src_bank,
    const int* __restrict__ src_lengths,
    const float* __restrict__ qa_sent_bank, const float* __restrict__ qa_word_bank,
    const int* __restrict__ qa_word_lengths,
    const float* __restrict__ w0, const float* __restrict__ w1,
    const float* __restrict__ w2, const float* __restrict__ w3,
    const float* __restrict__ w4, const float* __restrict__ w5,
    const float* __restrict__ bq_word, const float* __restrict__ bq_sent,
    const float* __restrict__ bq_pass,
    const float* __restrict__ v_word, const float* __restrict__ v_sent,
    const float* __restrict__ v_pass,
    float* __restrict__ wsf, ushort_t* __restrict__ Pg,
    ushort_t* __restrict__ Mtg, ushort_t* __restrict__ Wtg,
    int* __restrict__ bar, float* __restrict__ out)
{
    __shared__ __align__(16) char smem[8448];
    const int tid = threadIdx.x;
    const int lane = tid & 63, wv = tid >> 6;
    const int quad = lane >> 4, l16 = lane & 15;
    int* bcnt = bar;
    int* bgen = bar + 1;
    const int nblocks = gridDim.x;

    // ================= Phase A: transposes =================
    {
        float (*tile)[33] = (float(*)[33])smem;
        int tx = tid & 31, ty = tid >> 5;
        for (int job = blockIdx.x; job < 3648; job += gridDim.x) {
            if (job < 1536) {                       // weight tiles: 6 x 16 x 16
                int z = job >> 8, t = job & 255;
                int n0 = (t & 15) * 32, k0 = (t >> 4) * 32;
                const float* W;
                switch (z) { case 0: W = w0; break; case 1: W = w1; break;
                             case 2: W = w2; break; case 3: W = w3; break;
                             case 4: W = w4; break; default: W = w5; break; }
                ushort_t* Wt = Wtg + z * (D_ * D_);
#pragma unroll
                for (int a = 0; a < 4; ++a)
                    tile[ty + a * 8][tx] = W[(k0 + ty + a * 8) * D_ + n0 + tx];
                __syncthreads();
#pragma unroll
                for (int a = 0; a < 4; ++a)
                    Wt[(n0 + ty + a * 8) * D_ + k0 + tx] = f2b(tile[tx][ty + a * 8]);
            } else {                                // bank tiles: 4b x 33s0 x 16d0
                int j = job - 1536;
                int b = j / 528, r = j - b * 528;
                int s0 = (r % 33) * 32, d0 = (r / 33) * 32;
#pragma unroll
                for (int a = 0; a < 4; ++a) {
                    int s = s0 + ty + a * 8;
                    float val = 0.f;
                    if (s < SRC_) {
                        val = src_bank[(s * B_ + b) * D_ + d0 + tx];
                    } else if (s < NMEM_) {
                        int jj = s - SRC_; int se = jj / WORDS_; int wd = jj - se * WORDS_;
                        val = qa_word_bank[((wd * B_ + b) * SENTS_ + se) * D_ + d0 + tx];
                    }
                    tile[ty + a * 8][tx] = val;
                }
                __syncthreads();
                ushort_t* base = Mtg + (size_t)b * D_ * NK_;
#pragma unroll
                for (int a = 0; a < 4; ++a)
                    base[(size_t)(d0 + ty + a * 8) * NK_ + s0 + tx] = f2b(tile[tx][ty + a * 8]);
            }
            __syncthreads();
        }
    }
    gbar(bcnt, bgen, nblocks);

    // ================= Phase B: projections (MFMA) =================
    {
        short* At = (short*)smem;          // 64 x 32
        short* Bt = (short*)(smem + 4096); // 64 x 32
        int sm = tid >> 2, koff = (tid & 3) * 8;
        for (int job = blockIdx.x; job < 624; job += gridDim.x) {
            int z, mt, nt;
            if (job < 96)       { z = job / 32; int r = job & 31; mt = r >> 3; nt = r & 7; }
            else if (job < 416) { z = 3; int r = job - 96;  mt = r >> 3; nt = r & 7; }
            else if (job < 616) { z = 4; int r = job - 416; mt = r >> 3; nt = r & 7; }
            else                { z = 5; mt = 0; nt = job - 616; }
            int M, atype; const float* bias; float* C;
            switch (z) {
                case 0: M = 200;  atype = 0; bias = bq_word; C = wsf + OFF_WQ_WORD; break;
                case 1: M = 200;  atype = 0; bias = bq_sent; C = wsf + OFF_WQ_SENT; break;
                case 2: M = 200;  atype = 0; bias = bq_pass; C = wsf + OFF_WQ_PASS; break;
                case 3: M = 2560; atype = 1; bias = nullptr; C = wsf + OFF_UH_WORD; break;
                case 4: M = 1600; atype = 2; bias = nullptr; C = wsf + OFF_UH_SRC;  break;
                default: M = 64;  atype = 3; bias = nullptr; C = wsf + OFF_UH_SENT; break;
            }
            int m0 = mt * 64, n0 = nt * 64;
            const ushort_t* W = Wtg + z * (D_ * D_);
            const float* arow = nullptr;
            {
                int r = m0 + sm;
                if (r < M) {
                    if (atype == 0) arow = source + r * D_;
                    else if (atype == 1) { int b = r / NW_; int jj = r - b * NW_;
                                           int se = jj / WORDS_; int wd = jj - se * WORDS_;
                                           arow = qa_word_bank + ((wd * B_ + b) * SENTS_ + se) * D_; }
                    else if (atype == 2) { int b = r / SRC_; int jj = r - b * SRC_;
                                           arow = src_bank + (jj * B_ + b) * D_; }
                    else                 { int b = r >> 4; int s2 = r & 15;
                                           arow = qa_sent_bank + (s2 * B_ + b) * D_; }
                }
            }
            const ushort_t* wrow = W + (n0 + sm) * D_;
            f4v acc[4] = { {0.f,0.f,0.f,0.f}, {0.f,0.f,0.f,0.f},
                           {0.f,0.f,0.f,0.f}, {0.f,0.f,0.f,0.f} };
            for (int kk = 0; kk < 16; ++kk) {
                int k0 = kk * 32;
                union { ushort_t u[8]; int4 v; } pk;
                if (arow) {
                    float4 f0 = *(const float4*)(arow + k0 + koff);
                    float4 f1 = *(const float4*)(arow + k0 + koff + 4);
                    pk.u[0] = f2b(f0.x); pk.u[1] = f2b(f0.y);
                    pk.u[2] = f2b(f0.z); pk.u[3] = f2b(f0.w);
                    pk.u[4] = f2b(f1.x); pk.u[5] = f2b(f1.y);
                    pk.u[6] = f2b(f1.z); pk.u[7] = f2b(f1.w);
                } else {
                    pk.v = int4{0, 0, 0, 0};
                }
                int4 bv = *(const int4*)(wrow + k0 + koff);
                *(int4*)(At + sm * 32 + koff) = pk.v;
                *(int4*)(Bt + sm * 32 + koff) = bv;
                __syncthreads();
                s8v af = *(const s8v*)(At + (wv * 16 + l16) * 32 + quad * 8);
#pragma unroll
                for (int ng = 0; ng < 4; ++ng) {
                    s8v bf = *(const s8v*)(Bt + (ng * 16 + l16) * 32 + quad * 8);
                    acc[ng] = __builtin_amdgcn_mfma_f32_16x16x32_bf16(af, bf, acc[ng], 0, 0, 0);
                }
                __syncthreads();
            }
#pragma unroll
            for (int ng = 0; ng < 4; ++ng) {
                int col = n0 + ng * 16 + l16;
                float bb = bias ? bias[col] : 0.f;
#pragma unroll
                for (int rr = 0; rr < 4; ++rr) {
                    int row = m0 + wv * 16 + quad * 4 + rr;
                    if (row < M) C[row * D_ + col] = (acc[ng][rr] + bb) * C2L2E;
                }
            }
        }
    }
    gbar(bcnt, bgen, nblocks);

    // ================= Phase C: tanh scores =================
    {
        for (int job2 = blockIdx.x * 4 + wv; job2 < 8448; job2 += gridDim.x * 4) {
            int job = job2 >> 1, th = job2 & 1;
            int b = job / NJOB_, slot = job - b * NJOB_;
            const float* uh; const float* v; const float* wq; float* sco; int ostride;
            bool active = true;
            if (slot < SRC_) {
                active = (slot < src_lengths[b]);
                uh = wsf + OFF_UH_SRC + (b * SRC_ + slot) * D_;
                v = v_pass; wq = wsf + OFF_WQ_PASS + b * T_ * D_;
                sco = wsf + OFF_SC_SRC + b * T_ * SRC_ + slot; ostride = SRC_;
            } else if (slot < NMEM_) {
                int j = slot - SRC_;
                int se = j / WORDS_; int wd = j - se * WORDS_;
                active = (wd < qa_word_lengths[b * SENTS_ + se]);
                uh = wsf + OFF_UH_WORD + (b * NW_ + j) * D_;
                v = v_word; wq = wsf + OFF_WQ_WORD + b * T_ * D_;
                sco = wsf + OFF_SC_WORD + b * T_ * NW_ + j; ostride = NW_;
            } else {
                int s2 = slot - NMEM_;
                uh = wsf + OFF_UH_SENT + (b * SENTS_ + s2) * D_;
                v = v_sent; wq = wsf + OFF_WQ_SENT + b * T_ * D_;
                sco = wsf + OFF_SC_SENT + b * T_ * SENTS_ + s2; ostride = SENTS_;
            }
            if (!active) continue;
            int d0 = lane * 8;
            float4 u0 = *(const float4*)(uh + d0);
            float4 u1 = *(const float4*)(uh + d0 + 4);
            float uhr[8] = {u0.x, u0.y, u0.z, u0.w, u1.x, u1.y, u1.z, u1.w};
            float4 v0 = *(const float4*)(v + d0);
            float4 v1 = *(const float4*)(v + d0 + 4);
            float vr[8] = {v0.x, v0.y, v0.z, v0.w, v1.x, v1.y, v1.z, v1.w};
            float vs = ((vr[0] + vr[1]) + (vr[2] + vr[3])) + ((vr[4] + vr[5]) + (vr[6] + vr[7]));
#pragma unroll
            for (int off = 32; off > 0; off >>= 1) vs += __shfl_xor(vs, off, 64);
            // 25 t-columns in chunks of 13+12 (register-bounded, overlapped chains)
            score_chunk<13>(wq, th * 25,      ostride, lane, uhr, vr, vs, sco);
            score_chunk<12>(wq, th * 25 + 13, ostride, lane, uhr, vr, vs, sco);
        }
    }
    gbar(bcnt, bgen, nblocks);

    // ================= Phase D: softmax -> bf16 P =================
    {
        float* p = (float*)smem;               // 1040 floats
        float* red = (float*)(smem + 4160);    // 4 floats
        for (int bt = blockIdx.x; bt < 200; bt += gridDim.x) {
            int b = bt / T_, t = bt - b * T_;
            const float* sc_src  = wsf + OFF_SC_SRC  + bt * SRC_;
            const float* sc_word = wsf + OFF_SC_WORD + bt * NW_;
            const float* sc_sent = wsf + OFF_SC_SENT + bt * SENTS_;
            int slen = src_lengths[b];
            float mx = -3.0e38f;
            for (int j = tid; j < NMEM_; j += 256) {
                float val;
                if (j < SRC_) {
                    val = (j < slen) ? sc_src[j] : -1e30f;
                } else {
                    int jj = j - SRC_; int se = jj / WORDS_; int wd = jj - se * WORDS_;
                    float raw = sc_word[jj] * sc_sent[se];
                    val = (wd < qa_word_lengths[b * SENTS_ + se]) ? raw : -1e30f;
                }
                p[j] = val;
                mx = fmaxf(mx, val);
            }
#pragma unroll
            for (int off = 32; off > 0; off >>= 1) mx = fmaxf(mx, __shfl_xor(mx, off, 64));
            if (lane == 0) red[wv] = mx;
            __syncthreads();
            mx = fmaxf(fmaxf(red[0], red[1]), fmaxf(red[2], red[3]));
            __syncthreads();
            float lsum = 0.f;
            for (int j = tid; j < NMEM_; j += 256) {
                float e = __expf(p[j] - mx);
                p[j] = e; lsum += e;
            }
#pragma unroll
            for (int off = 32; off > 0; off >>= 1) lsum += __shfl_xor(lsum, off, 64);
            if (lane == 0) red[wv] = lsum;
            __syncthreads();
            float inv = 1.f / (red[0] + red[1] + red[2] + red[3]);
            ushort_t* prow = Pg + (size_t)(b * 64 + t) * NK_;
            for (int j = tid; j < NK_; j += 256)
                prow[j] = (j < NMEM_) ? f2b(p[j] * inv) : (ushort_t)0;
            __syncthreads();
        }
    }
    gbar(bcnt, bgen, nblocks);

    // ================= Phase E: context GEMM =================
    {
        short* At = (short*)smem;          // 64 x 32
        short* Bt = (short*)(smem + 4096); // 32 x 32
        int smA = tid >> 2, koffA = (tid & 3) * 8;
        int smB = tid >> 3, koffB = (tid & 7) * 4;
        for (int job = blockIdx.x; job < 64; job += gridDim.x) {
            int b = job >> 4, nt = job & 15;
            int n0 = nt * 32;
            const ushort_t* arow = Pg + (size_t)(b * 64 + smA) * NK_ + koffA;
            const ushort_t* brow = Mtg + ((size_t)(b * D_ + n0 + smB)) * NK_ + koffB;
            f4v acc[2] = { {0.f,0.f,0.f,0.f}, {0.f,0.f,0.f,0.f} };
            for (int kk = 0; kk < 33; ++kk) {
                int k0 = kk * 32;
                int4 av = *(const int4*)(arow + k0);
                int2 bv = *(const int2*)(brow + k0);
                *(int4*)(At + smA * 32 + koffA) = av;
                *(int2*)(Bt + smB * 32 + koffB) = bv;
                __syncthreads();
                s8v af = *(const s8v*)(At + (wv * 16 + l16) * 32 + quad * 8);
#pragma unroll
                for (int ng = 0; ng < 2; ++ng) {
                    s8v bf = *(const s8v*)(Bt + (ng * 16 + l16) * 32 + quad * 8);
                    acc[ng] = __builtin_amdgcn_mfma_f32_16x16x32_bf16(af, bf, acc[ng], 0, 0, 0);
                }
                __syncthreads();
            }
#pragma unroll
            for (int ng = 0; ng < 2; ++ng) {
                int col = n0 + ng * 16 + l16;
#pragma unroll
                for (int rr = 0; rr < 4; ++rr) {
                    int row = wv * 16 + quad * 4 + rr;   // t
                    if (row < T_) out[(size_t)(b * T_ + row) * D_ + col] = acc[ng][rr];
                }
            }
        }
    }
}

extern "C" void kernel_launch(void* const* d_in, const int* in_sizes, int n_in,
                              void* d_out, int out_size, void* d_ws, size_t ws_size,
                              hipStream_t stream)
{
    (void)in_sizes; (void)n_in; (void)out_size; (void)ws_size;
    const float* source          = (const float*)d_in[0];
    const float* src_bank        = (const float*)d_in[1];
    const int*   src_lengths     = (const int*)d_in[2];
    const float* qa_sent_bank    = (const float*)d_in[3];
    /* d_in[4] qa_sent_lengths unused (matches reference) */
    const float* qa_word_bank    = (const float*)d_in[5];
    const int*   qa_word_lengths = (const int*)d_in[6];
    const float* Wq_word = (const float*)d_in[7];
    const float* bq_word = (const float*)d_in[8];
    const float* Uc_word = (const float*)d_in[9];
    const float* v_word  = (const float*)d_in[10];
    const float* Wq_sent = (const float*)d_in[11];
    const float* bq_sent = (const float*)d_in[12];
    const float* Uc_sent = (const float*)d_in[13];
    const float* v_sent  = (const float*)d_in[14];
    const float* Wq_pass = (const float*)d_in[15];
    const float* bq_pass = (const float*)d_in[16];
    const float* Uc_pass = (const float*)d_in[17];
    const float* v_pass  = (const float*)d_in[18];

    float* wsf = (float*)d_ws;
    ushort_t* Pb  = (ushort_t*)((char*)d_ws + P_BYTE_OFF);
    ushort_t* mt  = (ushort_t*)((char*)d_ws + MT_BYTE_OFF);
    ushort_t* wt  = (ushort_t*)((char*)d_ws + WT_BYTE_OFF);
    int* bar      = (int*)((char*)d_ws + BAR_BYTE_OFF);
    float* out = (float*)d_out;

    // Barrier counters must start at 0 (ws is poisoned 0xAA before every call).
    hipMemsetAsync(bar, 0, 2 * sizeof(int), stream);

    // Size the cooperative grid from actual occupancy (R6 lesson).
    int nb = 0;
    hipError_t oerr = hipOccupancyMaxActiveBlocksPerMultiprocessor(&nb, mega, 256, 0);
    if (oerr != hipSuccess || nb < 1) nb = 1;
    int ncu = 0, dev = 0;
    if (hipGetDevice(&dev) != hipSuccess ||
        hipDeviceGetAttribute(&ncu, hipDeviceAttributeMultiprocessorCount, dev) != hipSuccess ||
        ncu < 1) ncu = 256;
    int gridn = nb * ncu;
    if (gridn > 1024) gridn = 1024;
    if (gridn < 1) gridn = 1;

    // Wt slot order matches phase-B z order:
    // 0:Wq_word 1:Wq_sent 2:Wq_pass 3:Uc_word 4:Uc_pass 5:Uc_sent
    void* args[] = {
        (void*)&source, (void*)&src_bank, (void*)&src_lengths,
        (void*)&qa_sent_bank, (void*)&qa_word_bank, (void*)&qa_word_lengths,
        (void*)&Wq_word, (void*)&Wq_sent, (void*)&Wq_pass,
        (void*)&Uc_word, (void*)&Uc_pass, (void*)&Uc_sent,
        (void*)&bq_word, (void*)&bq_sent, (void*)&bq_pass,
        (void*)&v_word, (void*)&v_sent, (void*)&v_pass,
        (void*)&wsf, (void*)&Pb, (void*)&mt, (void*)&wt, (void*)&bar, (void*)&out
    };
    hipLaunchCooperativeKernel((void*)mega, dim3(gridn), dim3(256), args, 0, stream);
}

// Round 9
// 488.230 us; speedup vs baseline: 1.0006x; 1.0006x over previous
//
#include <hip/hip_runtime.h>
#include <hip/hip_bf16.h>

// HierarchicalAttention: B=4,T=50,D=512, SRC=400, SENTS=16, WORDS=40.
// Single cooperative mega-kernel, 5 phases separated by a TWO-LEVEL TREE grid
// barrier. R7 (cg::grid.sync) and R8 (flat single-line barrier) both measured
// ~90-97us/barrier: 1024 serialized cross-fabric RMWs on one line (~90ns each).
// Tree: 32 groups x 32 blocks -> leaf arrivals on 32 separate lines (parallel),
// 32 root RMWs, gen broadcast. Expected ~7-10us/barrier.
//   A: transposes (weights W->bf16 Wt[n][k]; banks->bf16 Mt[b][d][s])
//   B: MFMA projections (outputs pre-scaled by 2*log2e)
//   C: tanh scores (sigmoid form; masked jobs skipped; 2 waves/job; 13+12 chunks)
//   D: hier combine + mask + softmax -> bf16 P
//   E: MFMA context GEMM (P x M -> out)

#define B_    4
#define T_    50
#define D_    512
#define SRC_  400
#define SENTS_ 16
#define WORDS_ 40
#define NW_   640      // SENTS*WORDS
#define NMEM_ 1040     // SRC + NW
#define NK_   1056     // NMEM padded to 32*33 for MFMA K-loop
#define NJOB_ 1056     // NMEM + SENTS (score jobs per batch)

#define C2L2E 2.8853900817779268f   // 2*log2(e): x -> exp2(C2L2E*x) = exp(2x)

typedef unsigned short ushort_t;
using s8v = __attribute__((ext_vector_type(8))) short;   // 8 bf16 (4 VGPRs)
using f4v = __attribute__((ext_vector_type(4))) float;   // MFMA accumulator

// ---- workspace layout ----
// f32 region (float offsets):
#define OFF_WQ_WORD 0
#define OFF_WQ_SENT 102400
#define OFF_WQ_PASS 204800
#define OFF_UH_SRC  307200
#define OFF_UH_WORD 1126400
#define OFF_UH_SENT 2437120
#define OFF_SC_SRC  2469888
#define OFF_SC_WORD 2549888
#define OFF_SC_SENT 2677888
// f32 region ends at float 2681088 = byte 10724352
// bf16 regions (byte offsets):
#define P_BYTE_OFF  10724352ull   // P[b][64][1056]  bf16 = 540672 B
#define MT_BYTE_OFF 11265024ull   // Mt[b][512][1056] bf16 = 4325376 B
#define WT_BYTE_OFF 15590400ull   // Wt[6][512][512] bf16 = 3145728 B
#define BAR_BYTE_OFF 18736128ull  // tree barrier: root line + 32 leaf lines

__device__ __forceinline__ ushort_t f2b(float f) {
    __hip_bfloat16 h = __float2bfloat16(f);   // RNE
    return *(ushort_t*)&h;
}

// Two-level sense-reversing grid barrier. gridDim.x must be a multiple of 32.
// bar layout (ints): [0]=root_cnt, [16]=root_gen, then per group g (0..31):
// [32+g*32]=leaf_cnt, [32+g*32+16]=leaf_gen  (64B line separation).
__device__ __forceinline__ void gbar(int* bar, int nblocks) {
    __syncthreads();
    if (threadIdx.x == 0) {
        __threadfence();   // publish this block's phase writes (agent scope)
        const int g = blockIdx.x >> 5;
        const int ngroups = nblocks >> 5;
        int* leaf_cnt = bar + 32 + g * 32;
        int* leaf_gen = bar + 32 + g * 32 + 16;
        int* root_cnt = bar;
        int* root_gen = bar + 16;
        int lg = __hip_atomic_load(leaf_gen, __ATOMIC_RELAXED, __HIP_MEMORY_SCOPE_AGENT);
        int arrived = __hip_atomic_fetch_add(leaf_cnt, 1, __ATOMIC_ACQ_REL,
                                             __HIP_MEMORY_SCOPE_AGENT);
        if (arrived == 31) {                 // group representative
            __hip_atomic_store(leaf_cnt, 0, __ATOMIC_RELAXED, __HIP_MEMORY_SCOPE_AGENT);
            int rg = __hip_atomic_load(root_gen, __ATOMIC_RELAXED, __HIP_MEMORY_SCOPE_AGENT);
            int rarr = __hip_atomic_fetch_add(root_cnt, 1, __ATOMIC_ACQ_REL,
                                              __HIP_MEMORY_SCOPE_AGENT);
            if (rarr == ngroups - 1) {       // last group: flip root
                __hip_atomic_store(root_cnt, 0, __ATOMIC_RELAXED, __HIP_MEMORY_SCOPE_AGENT);
                __hip_atomic_store(root_gen, rg + 1, __ATOMIC_RELEASE, __HIP_MEMORY_SCOPE_AGENT);
            } else {
                while (__hip_atomic_load(root_gen, __ATOMIC_ACQUIRE,
                                         __HIP_MEMORY_SCOPE_AGENT) == rg)
                    __builtin_amdgcn_s_sleep(2);
            }
            __hip_atomic_store(leaf_gen, lg + 1, __ATOMIC_RELEASE, __HIP_MEMORY_SCOPE_AGENT);
        } else {
            while (__hip_atomic_load(leaf_gen, __ATOMIC_ACQUIRE,
                                     __HIP_MEMORY_SCOPE_AGENT) == lg)
                __builtin_amdgcn_s_sleep(2);
        }
        __threadfence();
    }
    __syncthreads();
}

// Phase-C inner chunk: NT independent t-columns, one butterfly batch.
template<int NT>
__device__ __forceinline__ void score_chunk(
    const float* __restrict__ wqh, int tb, int ostride, int lane,
    const float uhr[8], const float vr[8], float vs,
    float* __restrict__ sco)
{
    int d0 = lane * 8;
    float acc[NT];
#pragma unroll
    for (int u = 0; u < NT; ++u) {
        const float* wr = wqh + (tb + u) * D_ + d0;
        float4 w0 = *(const float4*)(wr);
        float4 w1 = *(const float4*)(wr + 4);
        float wrr[8] = {w0.x, w0.y, w0.z, w0.w, w1.x, w1.y, w1.z, w1.w};
        float a = 0.f;
#pragma unroll
        for (int j = 0; j < 8; ++j) {
            float e = __builtin_amdgcn_exp2f(wrr[j] + uhr[j]);  // exp(2x)
            float r = __builtin_amdgcn_rcpf(e + 1.f);           // sigmoid(-2x)
            a = fmaf(vr[j], r, a);
        }
        acc[u] = a;
    }
#pragma unroll
    for (int off = 32; off > 0; off >>= 1) {
#pragma unroll
        for (int u = 0; u < NT; ++u)
            acc[u] += __shfl_xor(acc[u], off, 64);
    }
    if (lane == 0) {
#pragma unroll
        for (int u = 0; u < NT; ++u)
            sco[(tb + u) * ostride] = fmaf(-2.f, acc[u], vs);
    }
}

__global__ __launch_bounds__(256, 2) void mega(
    const float* __restrict__ source, const float* __restrict__ src_bank,
    const int* __restrict__ src_lengths,
    const float* __restrict__ qa_sent_bank, const float* __restrict__ qa_word_bank,
    const int* __restrict__ qa_word_lengths,
    const float* __restrict__ w0, const float* __restrict__ w1,
    const float* __restrict__ w2, const float* __restrict__ w3,
    const float* __restrict__ w4, const float* __restrict__ w5,
    const float* __restrict__ bq_word, const float* __restrict__ bq_sent,
    const float* __restrict__ bq_pass,
    const float* __restrict__ v_word, const float* __restrict__ v_sent,
    const float* __restrict__ v_pass,
    float* __restrict__ wsf, ushort_t* __restrict__ Pg,
    ushort_t* __restrict__ Mtg, ushort_t* __restrict__ Wtg,
    int* __restrict__ bar, float* __restrict__ out)
{
    __shared__ __align__(16) char smem[8448];
    const int tid = threadIdx.x;
    const int lane = tid & 63, wv = tid >> 6;
    const int quad = lane >> 4, l16 = lane & 15;
    const int nblocks = gridDim.x;

    // ================= Phase A: transposes =================
    {
        float (*tile)[33] = (float(*)[33])smem;
        int tx = tid & 31, ty = tid >> 5;
        for (int job = blockIdx.x; job < 3648; job += gridDim.x) {
            if (job < 1536) {                       // weight tiles: 6 x 16 x 16
                int z = job >> 8, t = job & 255;
                int n0 = (t & 15) * 32, k0 = (t >> 4) * 32;
                const float* W;
                switch (z) { case 0: W = w0; break; case 1: W = w1; break;
                             case 2: W = w2; break; case 3: W = w3; break;
                             case 4: W = w4; break; default: W = w5; break; }
                ushort_t* Wt = Wtg + z * (D_ * D_);
#pragma unroll
                for (int a = 0; a < 4; ++a)
                    tile[ty + a * 8][tx] = W[(k0 + ty + a * 8) * D_ + n0 + tx];
                __syncthreads();
#pragma unroll
                for (int a = 0; a < 4; ++a)
                    Wt[(n0 + ty + a * 8) * D_ + k0 + tx] = f2b(tile[tx][ty + a * 8]);
            } else {                                // bank tiles: 4b x 33s0 x 16d0
                int j = job - 1536;
                int b = j / 528, r = j - b * 528;
                int s0 = (r % 33) * 32, d0 = (r / 33) * 32;
#pragma unroll
                for (int a = 0; a < 4; ++a) {
                    int s = s0 + ty + a * 8;
                    float val = 0.f;
                    if (s < SRC_) {
                        val = src_bank[(s * B_ + b) * D_ + d0 + tx];
                    } else if (s < NMEM_) {
                        int jj = s - SRC_; int se = jj / WORDS_; int wd = jj - se * WORDS_;
                        val = qa_word_bank[((wd * B_ + b) * SENTS_ + se) * D_ + d0 + tx];
                    }
                    tile[ty + a * 8][tx] = val;
                }
                __syncthreads();
                ushort_t* base = Mtg + (size_t)b * D_ * NK_;
#pragma unroll
                for (int a = 0; a < 4; ++a)
                    base[(size_t)(d0 + ty + a * 8) * NK_ + s0 + tx] = f2b(tile[tx][ty + a * 8]);
            }
            __syncthreads();
        }
    }
    gbar(bar, nblocks);

    // ================= Phase B: projections (MFMA) =================
    {
        short* At = (short*)smem;          // 64 x 32
        short* Bt = (short*)(smem + 4096); // 64 x 32
        int sm = tid >> 2, koff = (tid & 3) * 8;
        for (int job = blockIdx.x; job < 624; job += gridDim.x) {
            int z, mt, nt;
            if (job < 96)       { z = job / 32; int r = job & 31; mt = r >> 3; nt = r & 7; }
            else if (job < 416) { z = 3; int r = job - 96;  mt = r >> 3; nt = r & 7; }
            else if (job < 616) { z = 4; int r = job - 416; mt = r >> 3; nt = r & 7; }
            else                { z = 5; mt = 0; nt = job - 616; }
            int M, atype; const float* bias; float* C;
            switch (z) {
                case 0: M = 200;  atype = 0; bias = bq_word; C = wsf + OFF_WQ_WORD; break;
                case 1: M = 200;  atype = 0; bias = bq_sent; C = wsf + OFF_WQ_SENT; break;
                case 2: M = 200;  atype = 0; bias = bq_pass; C = wsf + OFF_WQ_PASS; break;
                case 3: M = 2560; atype = 1; bias = nullptr; C = wsf + OFF_UH_WORD; break;
                case 4: M = 1600; atype = 2; bias = nullptr; C = wsf + OFF_UH_SRC;  break;
                default: M = 64;  atype = 3; bias = nullptr; C = wsf + OFF_UH_SENT; break;
            }
            int m0 = mt * 64, n0 = nt * 64;
            const ushort_t* W = Wtg + z * (D_ * D_);
            const float* arow = nullptr;
            {
                int r = m0 + sm;
                if (r < M) {
                    if (atype == 0) arow = source + r * D_;
                    else if (atype == 1) { int b = r / NW_; int jj = r - b * NW_;
                                           int se = jj / WORDS_; int wd = jj - se * WORDS_;
                                           arow = qa_word_bank + ((wd * B_ + b) * SENTS_ + se) * D_; }
                    else if (atype == 2) { int b = r / SRC_; int jj = r - b * SRC_;
                                           arow = src_bank + (jj * B_ + b) * D_; }
                    else                 { int b = r >> 4; int s2 = r & 15;
                                           arow = qa_sent_bank + (s2 * B_ + b) * D_; }
                }
            }
            const ushort_t* wrow = W + (n0 + sm) * D_;
            f4v acc[4] = { {0.f,0.f,0.f,0.f}, {0.f,0.f,0.f,0.f},
                           {0.f,0.f,0.f,0.f}, {0.f,0.f,0.f,0.f} };
            for (int kk = 0; kk < 16; ++kk) {
                int k0 = kk * 32;
                union { ushort_t u[8]; int4 v; } pk;
                if (arow) {
                    float4 f0 = *(const float4*)(arow + k0 + koff);
                    float4 f1 = *(const float4*)(arow + k0 + koff + 4);
                    pk.u[0] = f2b(f0.x); pk.u[1] = f2b(f0.y);
                    pk.u[2] = f2b(f0.z); pk.u[3] = f2b(f0.w);
                    pk.u[4] = f2b(f1.x); pk.u[5] = f2b(f1.y);
                    pk.u[6] = f2b(f1.z); pk.u[7] = f2b(f1.w);
                } else {
                    pk.v = int4{0, 0, 0, 0};
                }
                int4 bv = *(const int4*)(wrow + k0 + koff);
                *(int4*)(At + sm * 32 + koff) = pk.v;
                *(int4*)(Bt + sm * 32 + koff) = bv;
                __syncthreads();
                s8v af = *(const s8v*)(At + (wv * 16 + l16) * 32 + quad * 8);
#pragma unroll
                for (int ng = 0; ng < 4; ++ng) {
                    s8v bf = *(const s8v*)(Bt + (ng * 16 + l16) * 32 + quad * 8);
                    acc[ng] = __builtin_amdgcn_mfma_f32_16x16x32_bf16(af, bf, acc[ng], 0, 0, 0);
                }
                __syncthreads();
            }
#pragma unroll
            for (int ng = 0; ng < 4; ++ng) {
                int col = n0 + ng * 16 + l16;
                float bb = bias ? bias[col] : 0.f;
#pragma unroll
                for (int rr = 0; rr < 4; ++rr) {
                    int row = m0 + wv * 16 + quad * 4 + rr;
                    if (row < M) C[row * D_ + col] = (acc[ng][rr] + bb) * C2L2E;
                }
            }
        }
    }
    gbar(bar, nblocks);

    // ================= Phase C: tanh scores =================
    {
        for (int job2 = blockIdx.x * 4 + wv; job2 < 8448; job2 += gridDim.x * 4) {
            int job = job2 >> 1, th = job2 & 1;
            int b = job / NJOB_, slot = job - b * NJOB_;
            const float* uh; const float* v; const float* wq; float* sco; int ostride;
            bool active = true;
            if (slot < SRC_) {
                active = (slot < src_lengths[b]);
                uh = wsf + OFF_UH_SRC + (b * SRC_ + slot) * D_;
                v = v_pass; wq = wsf + OFF_WQ_PASS + b * T_ * D_;
                sco = wsf + OFF_SC_SRC + b * T_ * SRC_ + slot; ostride = SRC_;
            } else if (slot < NMEM_) {
                int j = slot - SRC_;
                int se = j / WORDS_; int wd = j - se * WORDS_;
                active = (wd < qa_word_lengths[b * SENTS_ + se]);
                uh = wsf + OFF_UH_WORD + (b * NW_ + j) * D_;
                v = v_word; wq = wsf + OFF_WQ_WORD + b * T_ * D_;
                sco = wsf + OFF_SC_WORD + b * T_ * NW_ + j; ostride = NW_;
            } else {
                int s2 = slot - NMEM_;
                uh = wsf + OFF_UH_SENT + (b * SENTS_ + s2) * D_;
                v = v_sent; wq = wsf + OFF_WQ_SENT + b * T_ * D_;
                sco = wsf + OFF_SC_SENT + b * T_ * SENTS_ + s2; ostride = SENTS_;
            }
            if (!active) continue;
            int d0 = lane * 8;
            float4 u0 = *(const float4*)(uh + d0);
            float4 u1 = *(const float4*)(uh + d0 + 4);
            float uhr[8] = {u0.x, u0.y, u0.z, u0.w, u1.x, u1.y, u1.z, u1.w};
            float4 v0 = *(const float4*)(v + d0);
            float4 v1 = *(const float4*)(v + d0 + 4);
            float vr[8] = {v0.x, v0.y, v0.z, v0.w, v1.x, v1.y, v1.z, v1.w};
            float vs = ((vr[0] + vr[1]) + (vr[2] + vr[3])) + ((vr[4] + vr[5]) + (vr[6] + vr[7]));
#pragma unroll
            for (int off = 32; off > 0; off >>= 1) vs += __shfl_xor(vs, off, 64);
            // 25 t-columns in chunks of 13+12 (register-bounded, overlapped chains)
            score_chunk<13>(wq, th * 25,      ostride, lane, uhr, vr, vs, sco);
            score_chunk<12>(wq, th * 25 + 13, ostride, lane, uhr, vr, vs, sco);
        }
    }
    gbar(bar, nblocks);

    // ================= Phase D: softmax -> bf16 P =================
    {
        float* p = (float*)smem;               // 1040 floats
        float* red = (float*)(smem + 4160);    // 4 floats
        for (int bt = blockIdx.x; bt < 200; bt += gridDim.x) {
            int b = bt / T_, t = bt - b * T_;
            const float* sc_src  = wsf + OFF_SC_SRC  + bt * SRC_;
            const float* sc_word = wsf + OFF_SC_WORD + bt * NW_;
            const float* sc_sent = wsf + OFF_SC_SENT + bt * SENTS_;
            int slen = src_lengths[b];
            float mx = -3.0e38f;
            for (int j = tid; j < NMEM_; j += 256) {
                float val;
                if (j < SRC_) {
                    val = (j < slen) ? sc_src[j] : -1e30f;
                } else {
                    int jj = j - SRC_; int se = jj / WORDS_; int wd = jj - se * WORDS_;
                    float raw = sc_word[jj] * sc_sent[se];
                    val = (wd < qa_word_lengths[b * SENTS_ + se]) ? raw : -1e30f;
                }
                p[j] = val;
                mx = fmaxf(mx, val);
            }
#pragma unroll
            for (int off = 32; off > 0; off >>= 1) mx = fmaxf(mx, __shfl_xor(mx, off, 64));
            if (lane == 0) red[wv] = mx;
            __syncthreads();
            mx = fmaxf(fmaxf(red[0], red[1]), fmaxf(red[2], red[3]));
            __syncthreads();
            float lsum = 0.f;
            for (int j = tid; j < NMEM_; j += 256) {
                float e = __expf(p[j] - mx);
                p[j] = e; lsum += e;
            }
#pragma unroll
            for (int off = 32; off > 0; off >>= 1) lsum += __shfl_xor(lsum, off, 64);
            if (lane == 0) red[wv] = lsum;
            __syncthreads();
            float inv = 1.f / (red[0] + red[1] + red[2] + red[3]);
            ushort_t* prow = Pg + (size_t)(b * 64 + t) * NK_;
            for (int j = tid; j < NK_; j += 256)
                prow[j] = (j < NMEM_) ? f2b(p[j] * inv) : (ushort_t)0;
            __syncthreads();
        }
    }
    gbar(bar, nblocks);

    // ================= Phase E: context GEMM =================
    {
        short* At = (short*)smem;          // 64 x 32
        short* Bt = (short*)(smem + 4096); // 32 x 32
        int smA = tid >> 2, koffA = (tid & 3) * 8;
        int smB = tid >> 3, koffB = (tid & 7) * 4;
        for (int job = blockIdx.x; job < 64; job += gridDim.x) {
            int b = job >> 4, nt = job & 15;
            int n0 = nt * 32;
            const ushort_t* arow = Pg + (size_t)(b * 64 + smA) * NK_ + koffA;
            const ushort_t* brow = Mtg + ((size_t)(b * D_ + n0 + smB)) * NK_ + koffB;
            f4v acc[2] = { {0.f,0.f,0.f,0.f}, {0.f,0.f,0.f,0.f} };
            for (int kk = 0; kk < 33; ++kk) {
                int k0 = kk * 32;
                int4 av = *(const int4*)(arow + k0);
                int2 bv = *(const int2*)(brow + k0);
                *(int4*)(At + smA * 32 + koffA) = av;
                *(int2*)(Bt + smB * 32 + koffB) = bv;
                __syncthreads();
                s8v af = *(const s8v*)(At + (wv * 16 + l16) * 32 + quad * 8);
#pragma unroll
                for (int ng = 0; ng < 2; ++ng) {
                    s8v bf = *(const s8v*)(Bt + (ng * 16 + l16) * 32 + quad * 8);
                    acc[ng] = __builtin_amdgcn_mfma_f32_16x16x32_bf16(af, bf, acc[ng], 0, 0, 0);
                }
                __syncthreads();
            }
#pragma unroll
            for (int ng = 0; ng < 2; ++ng) {
                int col = n0 + ng * 16 + l16;
#pragma unroll
                for (int rr = 0; rr < 4; ++rr) {
                    int row = wv * 16 + quad * 4 + rr;   // t
                    if (row < T_) out[(size_t)(b * T_ + row) * D_ + col] = acc[ng][rr];
                }
            }
        }
    }
}

extern "C" void kernel_launch(void* const* d_in, const int* in_sizes, int n_in,
                              void* d_out, int out_size, void* d_ws, size_t ws_size,
                              hipStream_t stream)
{
    (void)in_sizes; (void)n_in; (void)out_size; (void)ws_size;
    const float* source          = (const float*)d_in[0];
    const float* src_bank        = (const float*)d_in[1];
    const int*   src_lengths     = (const int*)d_in[2];
    const float* qa_sent_bank    = (const float*)d_in[3];
    /* d_in[4] qa_sent_lengths unused (matches reference) */
    const float* qa_word_bank    = (const float*)d_in[5];
    const int*   qa_word_lengths = (const int*)d_in[6];
    const float* Wq_word = (const float*)d_in[7];
    const float* bq_word = (const float*)d_in[8];
    const float* Uc_word = (const float*)d_in[9];
    const float* v_word  = (const float*)d_in[10];
    const float* Wq_sent = (const float*)d_in[11];
    const float* bq_sent = (const float*)d_in[12];
    const float* Uc_sent = (const float*)d_in[13];
    const float* v_sent  = (const float*)d_in[14];
    const float* Wq_pass = (const float*)d_in[15];
    const float* bq_pass = (const float*)d_in[16];
    const float* Uc_pass = (const float*)d_in[17];
    const float* v_pass  = (const float*)d_in[18];

    float* wsf = (float*)d_ws;
    ushort_t* Pb  = (ushort_t*)((char*)d_ws + P_BYTE_OFF);
    ushort_t* mt  = (ushort_t*)((char*)d_ws + MT_BYTE_OFF);
    ushort_t* wt  = (ushort_t*)((char*)d_ws + WT_BYTE_OFF);
    int* bar      = (int*)((char*)d_ws + BAR_BYTE_OFF);
    float* out = (float*)d_out;

    // Tree-barrier state (root line + 32 leaf lines) must start at 0.
    hipMemsetAsync(bar, 0, (32 + 32 * 32) * sizeof(int), stream);

    // Size the cooperative grid from actual occupancy (R6 lesson), rounded to
    // a multiple of 32 so every barrier group is full.
    int nb = 0;
    hipError_t oerr = hipOccupancyMaxActiveBlocksPerMultiprocessor(&nb, mega, 256, 0);
    if (oerr != hipSuccess || nb < 1) nb = 1;
    int ncu = 0, dev = 0;
    if (hipGetDevice(&dev) != hipSuccess ||
        hipDeviceGetAttribute(&ncu, hipDeviceAttributeMultiprocessorCount, dev) != hipSuccess ||
        ncu < 1) ncu = 256;
    int gridn = nb * ncu;
    if (gridn > 1024) gridn = 1024;
    gridn &= ~31;
    if (gridn < 32) gridn = 32;

    // Wt slot order matches phase-B z order:
    // 0:Wq_word 1:Wq_sent 2:Wq_pass 3:Uc_word 4:Uc_pass 5:Uc_sent
    void* args[] = {
        (void*)&source, (void*)&src_bank, (void*)&src_lengths,
        (void*)&qa_sent_bank, (void*)&qa_word_bank, (void*)&qa_word_lengths,
        (void*)&Wq_word, (void*)&Wq_sent, (void*)&Wq_pass,
        (void*)&Uc_word, (void*)&Uc_pass, (void*)&Uc_sent,
        (void*)&bq_word, (void*)&bq_sent, (void*)&bq_pass,
        (void*)&v_word, (void*)&v_sent, (void*)&v_pass,
        (void*)&wsf, (void*)&Pb, (void*)&mt, (void*)&wt, (void*)&bar, (void*)&out
    };
    hipLaunchCooperativeKernel((void*)mega, dim3(gridn), dim3(256), args, 0, stream);
}

// Round 10
// 168.738 us; speedup vs baseline: 2.8952x; 2.8934x over previous
//
#include <hip/hip_runtime.h>
#include <hip/hip_bf16.h>

// HierarchicalAttention: B=4,T=50,D=512, SRC=400, SENTS=16, WORDS=40.
// All float inputs are FLOAT32 (reference dtype). Output float32.
// 4 dispatches (mega-kernel abandoned: grid-wide sync costs ~97us on 8-XCD
// fabric regardless of barrier implementation — R7/R8/R9):
//   k1   MFMA projections; weights transposed in-kernel via LDS (no Wt pass)
//   k2   tanh scores (sigmoid form; masked jobs whole-block exit; 4 waves/job)
//   k3a  hier combine + mask + softmax -> bf16 P
//   k3c  context GEMM; banks transposed in-kernel via LDS (no Mt pass)

#define B_    4
#define T_    50
#define D_    512
#define SRC_  400
#define SENTS_ 16
#define WORDS_ 40
#define NW_   640      // SENTS*WORDS
#define NMEM_ 1040     // SRC + NW
#define NK_   1056     // NMEM padded to 32*33 for MFMA K-loop
#define NJOB_ 1056     // NMEM + SENTS (score jobs per batch)

#define C2L2E 2.8853900817779268f   // 2*log2(e): x -> exp2(C2L2E*x) = exp(2x)

typedef unsigned short ushort_t;
using s8v = __attribute__((ext_vector_type(8))) short;   // 8 bf16 (4 VGPRs)
using f4v = __attribute__((ext_vector_type(4))) float;   // MFMA accumulator

// ---- workspace layout ----
// f32 region (float offsets):
#define OFF_WQ_WORD 0
#define OFF_WQ_SENT 102400
#define OFF_WQ_PASS 204800
#define OFF_UH_SRC  307200
#define OFF_UH_WORD 1126400
#define OFF_UH_SENT 2437120
#define OFF_SC_SRC  2469888
#define OFF_SC_WORD 2549888
#define OFF_SC_SENT 2677888
// f32 region ends at float 2681088 = byte 10724352
#define P_BYTE_OFF  10724352ull   // P[b][64][1056] bf16 = 540672 B

__device__ __forceinline__ ushort_t f2b(float f) {
    __hip_bfloat16 h = __float2bfloat16(f);   // RNE
    return *(ushort_t*)&h;
}

// ---------------- k1: projections via bf16 MFMA, W transposed in-kernel ------
// grid (8 n-tiles, 40 m-tiles, 6 segments), 256 thr. Tile 64x64, K=512.
__global__ __launch_bounds__(256) void k1_gemm(
    const float* __restrict__ source, const float* __restrict__ src_bank,
    const float* __restrict__ qa_sent_bank, const float* __restrict__ qa_word_bank,
    const float* __restrict__ w0, const float* __restrict__ w1,
    const float* __restrict__ w2, const float* __restrict__ w3,
    const float* __restrict__ w4, const float* __restrict__ w5,
    const float* __restrict__ bq_word, const float* __restrict__ bq_sent,
    const float* __restrict__ bq_pass,
    float* __restrict__ wsf)
{
    __shared__ float ftile[32][65];   // W staging (f32, +1 pad col)
    __shared__ short At[64 * 32];
    __shared__ short Bt[64 * 32];
    int z = blockIdx.z;
    int M, atype; const float* bias; float* C; const float* W;
    switch (z) {
        case 0: M = 200;  atype = 0; bias = bq_word; C = wsf + OFF_WQ_WORD; W = w0; break;
        case 1: M = 200;  atype = 0; bias = bq_sent; C = wsf + OFF_WQ_SENT; W = w1; break;
        case 2: M = 200;  atype = 0; bias = bq_pass; C = wsf + OFF_WQ_PASS; W = w2; break;
        case 3: M = 2560; atype = 1; bias = nullptr; C = wsf + OFF_UH_WORD; W = w3; break;
        case 4: M = 1600; atype = 2; bias = nullptr; C = wsf + OFF_UH_SRC;  W = w4; break;
        default: M = 64;  atype = 3; bias = nullptr; C = wsf + OFF_UH_SENT; W = w5; break;
    }
    int m0 = blockIdx.y * 64;
    if (m0 >= M) return;
    int n0 = blockIdx.x * 64;

    int tid = threadIdx.x;
    int lane = tid & 63, wv = tid >> 6;
    int quad = lane >> 4, l16 = lane & 15;
    int sm = tid >> 2, koff = (tid & 3) * 8;   // A staging: row sm, 8-elem chunk
    int wr = tid >> 3, wc = (tid & 7) * 8;     // W load: k-row wr, 8 n-cols at wc
    int tn = tid >> 2, tk = (tid & 3) * 8;     // W transpose out: n-row tn, 8 k at tk

    const float* arow = nullptr;
    {
        int r = m0 + sm;
        if (r < M) {
            if (atype == 0) arow = source + r * D_;
            else if (atype == 1) { int b = r / NW_; int j = r - b * NW_;
                                   int se = j / WORDS_; int wd = j - se * WORDS_;
                                   arow = qa_word_bank + ((wd * B_ + b) * SENTS_ + se) * D_; }
            else if (atype == 2) { int b = r / SRC_; int j = r - b * SRC_;
                                   arow = src_bank + (j * B_ + b) * D_; }
            else                 { int b = r >> 4; int s2 = r & 15;
                                   arow = qa_sent_bank + (s2 * B_ + b) * D_; }
        }
    }

    f4v acc[4] = { {0.f,0.f,0.f,0.f}, {0.f,0.f,0.f,0.f},
                   {0.f,0.f,0.f,0.f}, {0.f,0.f,0.f,0.f} };

    for (int kk = 0; kk < 16; ++kk) {
        int k0 = kk * 32;
        // A: pack 8 f32 -> bf16
        union { ushort_t u[8]; int4 v; } pk;
        if (arow) {
            float4 f0 = *(const float4*)(arow + k0 + koff);
            float4 f1 = *(const float4*)(arow + k0 + koff + 4);
            pk.u[0] = f2b(f0.x); pk.u[1] = f2b(f0.y);
            pk.u[2] = f2b(f0.z); pk.u[3] = f2b(f0.w);
            pk.u[4] = f2b(f1.x); pk.u[5] = f2b(f1.y);
            pk.u[6] = f2b(f1.z); pk.u[7] = f2b(f1.w);
        } else {
            pk.v = int4{0, 0, 0, 0};
        }
        // W: coalesced f32 read of 32k x 64n tile
        const float* wsrc = W + (size_t)(k0 + wr) * D_ + n0 + wc;
        float4 g0 = *(const float4*)(wsrc);
        float4 g1 = *(const float4*)(wsrc + 4);
        *(int4*)(At + sm * 32 + koff) = pk.v;
        *(float4*)(&ftile[wr][wc]) = g0;
        *(float4*)(&ftile[wr][wc + 4]) = g1;
        __syncthreads();
        // W transpose: Bt[n][k] bf16
        union { ushort_t u[8]; int4 v; } tb;
#pragma unroll
        for (int i = 0; i < 8; ++i) tb.u[i] = f2b(ftile[tk + i][tn]);
        *(int4*)(Bt + tn * 32 + tk) = tb.v;
        __syncthreads();
        s8v af = *(const s8v*)(At + (wv * 16 + l16) * 32 + quad * 8);
#pragma unroll
        for (int ng = 0; ng < 4; ++ng) {
            s8v bf = *(const s8v*)(Bt + (ng * 16 + l16) * 32 + quad * 8);
            acc[ng] = __builtin_amdgcn_mfma_f32_16x16x32_bf16(af, bf, acc[ng], 0, 0, 0);
        }
        __syncthreads();
    }
    // epilogue: D col = lane&15, row = quad*4 + r; pre-scale by 2*log2e for k2
#pragma unroll
    for (int ng = 0; ng < 4; ++ng) {
        int col = n0 + ng * 16 + l16;
        float bb = bias ? bias[col] : 0.f;
#pragma unroll
        for (int rr = 0; rr < 4; ++rr) {
            int row = m0 + wv * 16 + quad * 4 + rr;
            if (row < M) C[row * D_ + col] = (acc[ng][rr] + bb) * C2L2E;
        }
    }
}

// ---------------- k2: additive-attention scores ----------------
// One job per block; 4 waves split t as 13/13/12/12. Masked jobs: whole-block
// exit (value never read by k3a). score = Vsum - 2*sum v[d]*sigmoid(-2x).
template<int NT>
__device__ __forceinline__ void score_chunk(
    const float* __restrict__ wq, int tb, int ostride, int lane,
    const float uhr[8], const float vr[8], float vs,
    float* __restrict__ sco)
{
    int d0 = lane * 8;
    float acc[NT];
#pragma unroll
    for (int u = 0; u < NT; ++u) {
        const float* wr = wq + (tb + u) * D_ + d0;
        float4 w0 = *(const float4*)(wr);
        float4 w1 = *(const float4*)(wr + 4);
        float wrr[8] = {w0.x, w0.y, w0.z, w0.w, w1.x, w1.y, w1.z, w1.w};
        float a = 0.f;
#pragma unroll
        for (int j = 0; j < 8; ++j) {
            float e = __builtin_amdgcn_exp2f(wrr[j] + uhr[j]);  // exp(2x)
            float r = __builtin_amdgcn_rcpf(e + 1.f);           // sigmoid(-2x)
            a = fmaf(vr[j], r, a);
        }
        acc[u] = a;
    }
#pragma unroll
    for (int off = 32; off > 0; off >>= 1) {
#pragma unroll
        for (int u = 0; u < NT; ++u)
            acc[u] += __shfl_xor(acc[u], off, 64);
    }
    if (lane == 0) {
#pragma unroll
        for (int u = 0; u < NT; ++u)
            sco[(tb + u) * ostride] = fmaf(-2.f, acc[u], vs);
    }
}

__global__ __launch_bounds__(256) void k2_scores(
    const float* __restrict__ v_word, const float* __restrict__ v_sent,
    const float* __restrict__ v_pass,
    const int* __restrict__ src_lengths, const int* __restrict__ qa_word_lengths,
    float* __restrict__ wsf)
{
    int lane = threadIdx.x & 63, th = threadIdx.x >> 6;   // th = t-quarter
    int job = blockIdx.x;                                  // 4224 jobs
    int b = job / NJOB_, slot = job - b * NJOB_;
    const float* uh; const float* v; const float* wq; float* sco; int ostride;
    if (slot < SRC_) {
        if (slot >= src_lengths[b]) return;                // whole-block exit
        uh = wsf + OFF_UH_SRC + (b * SRC_ + slot) * D_;
        v = v_pass; wq = wsf + OFF_WQ_PASS + b * T_ * D_;
        sco = wsf + OFF_SC_SRC + b * T_ * SRC_ + slot; ostride = SRC_;
    } else if (slot < NMEM_) {
        int j = slot - SRC_;
        int se = j / WORDS_; int wd = j - se * WORDS_;
        if (wd >= qa_word_lengths[b * SENTS_ + se]) return; // whole-block exit
        uh = wsf + OFF_UH_WORD + (b * NW_ + j) * D_;
        v = v_word; wq = wsf + OFF_WQ_WORD + b * T_ * D_;
        sco = wsf + OFF_SC_WORD + b * T_ * NW_ + j; ostride = NW_;
    } else {
        int s2 = slot - NMEM_;
        uh = wsf + OFF_UH_SENT + (b * SENTS_ + s2) * D_;
        v = v_sent; wq = wsf + OFF_WQ_SENT + b * T_ * D_;
        sco = wsf + OFF_SC_SENT + b * T_ * SENTS_ + s2; ostride = SENTS_;
    }
    int d0 = lane * 8;
    float4 u0 = *(const float4*)(uh + d0);
    float4 u1 = *(const float4*)(uh + d0 + 4);
    float uhr[8] = {u0.x, u0.y, u0.z, u0.w, u1.x, u1.y, u1.z, u1.w};
    float4 v0 = *(const float4*)(v + d0);
    float4 v1 = *(const float4*)(v + d0 + 4);
    float vr[8] = {v0.x, v0.y, v0.z, v0.w, v1.x, v1.y, v1.z, v1.w};
    float vs = ((vr[0] + vr[1]) + (vr[2] + vr[3])) + ((vr[4] + vr[5]) + (vr[6] + vr[7]));
#pragma unroll
    for (int off = 32; off > 0; off >>= 1) vs += __shfl_xor(vs, off, 64);

    // t split 13/13/12/12 across the 4 waves
    if (th == 0)      score_chunk<13>(wq, 0,  ostride, lane, uhr, vr, vs, sco);
    else if (th == 1) score_chunk<13>(wq, 13, ostride, lane, uhr, vr, vs, sco);
    else if (th == 2) score_chunk<12>(wq, 26, ostride, lane, uhr, vr, vs, sco);
    else              score_chunk<12>(wq, 38, ostride, lane, uhr, vr, vs, sco);
}

// ---------------- k3a: hier combine + mask + softmax -> bf16 P[b][64][1056] --
__global__ __launch_bounds__(256) void k3a_softmax(
    const int* __restrict__ src_lengths, const int* __restrict__ qa_word_lengths,
    const float* __restrict__ wsf, ushort_t* __restrict__ P)
{
    __shared__ float p[NMEM_];
    __shared__ float red[4];
    int tid = threadIdx.x, lane = tid & 63, wv = tid >> 6;
    int bt = blockIdx.x, b = bt / T_, t = bt - b * T_;
    const float* sc_src  = wsf + OFF_SC_SRC  + bt * SRC_;
    const float* sc_word = wsf + OFF_SC_WORD + bt * NW_;
    const float* sc_sent = wsf + OFF_SC_SENT + bt * SENTS_;
    int slen = src_lengths[b];
    float mx = -3.0e38f;
    for (int j = tid; j < NMEM_; j += 256) {
        float val;
        if (j < SRC_) {
            val = (j < slen) ? sc_src[j] : -1e30f;
        } else {
            int jj = j - SRC_; int se = jj / WORDS_; int wd = jj - se * WORDS_;
            float raw = sc_word[jj] * sc_sent[se];
            val = (wd < qa_word_lengths[b * SENTS_ + se]) ? raw : -1e30f;
        }
        p[j] = val;
        mx = fmaxf(mx, val);
    }
#pragma unroll
    for (int off = 32; off > 0; off >>= 1) mx = fmaxf(mx, __shfl_xor(mx, off, 64));
    if (lane == 0) red[wv] = mx;
    __syncthreads();
    mx = fmaxf(fmaxf(red[0], red[1]), fmaxf(red[2], red[3]));
    __syncthreads();
    float lsum = 0.f;
    for (int j = tid; j < NMEM_; j += 256) {
        float e = __expf(p[j] - mx);
        p[j] = e; lsum += e;
    }
#pragma unroll
    for (int off = 32; off > 0; off >>= 1) lsum += __shfl_xor(lsum, off, 64);
    if (lane == 0) red[wv] = lsum;
    __syncthreads();
    float inv = 1.f / (red[0] + red[1] + red[2] + red[3]);
    ushort_t* prow = P + (size_t)(b * 64 + t) * NK_;
    for (int j = tid; j < NK_; j += 256)
        prow[j] = (j < NMEM_) ? f2b(p[j] * inv) : (ushort_t)0;
}

// ---------------- k3c: context GEMM, banks transposed in-kernel --------------
// grid (16 d-tiles, 4 b), 256 thr. C[b][t][d] = sum_s P[t,s]*M[s,d]. K=1056.
__global__ __launch_bounds__(256) void k3c_gemm(
    const ushort_t* __restrict__ P,
    const float* __restrict__ src_bank, const float* __restrict__ qa_word_bank,
    float* __restrict__ out)
{
    __shared__ float ftile[32][33];   // bank staging (f32, s-major)
    __shared__ short At[64 * 32];
    __shared__ short Bt[32 * 32];
    int b = blockIdx.y;
    int n0 = blockIdx.x * 32;
    int tid = threadIdx.x;
    int lane = tid & 63, wv = tid >> 6;
    int quad = lane >> 4, l16 = lane & 15;
    int smA = tid >> 2, koffA = (tid & 3) * 8;  // A: 64 rows x 32k, int4/thread
    int br = tid >> 3, bc = (tid & 7) * 4;      // bank load: s-row br, 4 d at bc
    int td = tid >> 3, ts = (tid & 7) * 4;      // transpose out: d-row td, 4 s at ts

    const ushort_t* arow = P + (size_t)(b * 64 + smA) * NK_ + koffA;

    f4v acc[2] = { {0.f,0.f,0.f,0.f}, {0.f,0.f,0.f,0.f} };

    for (int kk = 0; kk < 33; ++kk) {
        int s0 = kk * 32;
        int4 av = *(const int4*)(arow + s0);
        // bank row decode + coalesced f32 read of 32s x 32d tile
        int s = s0 + br;
        float4 bv = {0.f, 0.f, 0.f, 0.f};
        if (s < SRC_) {
            bv = *(const float4*)(src_bank + (size_t)(s * B_ + b) * D_ + n0 + bc);
        } else if (s < NMEM_) {
            int jj = s - SRC_; int se = jj / WORDS_; int wd = jj - se * WORDS_;
            bv = *(const float4*)(qa_word_bank + ((size_t)(wd * B_ + b) * SENTS_ + se) * D_ + n0 + bc);
        }
        *(int4*)(At + smA * 32 + koffA) = av;
        *(float4*)(&ftile[br][bc]) = bv;
        __syncthreads();
        // transpose: Bt[d][s] bf16
        union { ushort_t u[4]; int2 v; } tb;
#pragma unroll
        for (int i = 0; i < 4; ++i) tb.u[i] = f2b(ftile[ts + i][td]);
        *(int2*)(Bt + td * 32 + ts) = tb.v;
        __syncthreads();
        s8v af = *(const s8v*)(At + (wv * 16 + l16) * 32 + quad * 8);
#pragma unroll
        for (int ng = 0; ng < 2; ++ng) {
            s8v bf = *(const s8v*)(Bt + (ng * 16 + l16) * 32 + quad * 8);
            acc[ng] = __builtin_amdgcn_mfma_f32_16x16x32_bf16(af, bf, acc[ng], 0, 0, 0);
        }
        __syncthreads();
    }
#pragma unroll
    for (int ng = 0; ng < 2; ++ng) {
        int col = n0 + ng * 16 + l16;
#pragma unroll
        for (int rr = 0; rr < 4; ++rr) {
            int row = wv * 16 + quad * 4 + rr;   // t
            if (row < T_) out[(size_t)(b * T_ + row) * D_ + col] = acc[ng][rr];
        }
    }
}

extern "C" void kernel_launch(void* const* d_in, const int* in_sizes, int n_in,
                              void* d_out, int out_size, void* d_ws, size_t ws_size,
                              hipStream_t stream)
{
    (void)in_sizes; (void)n_in; (void)out_size; (void)ws_size;
    const float* source          = (const float*)d_in[0];
    const float* src_bank        = (const float*)d_in[1];
    const int*   src_lengths     = (const int*)d_in[2];
    const float* qa_sent_bank    = (const float*)d_in[3];
    /* d_in[4] qa_sent_lengths unused (matches reference) */
    const float* qa_word_bank    = (const float*)d_in[5];
    const int*   qa_word_lengths = (const int*)d_in[6];
    const float* Wq_word = (const float*)d_in[7];
    const float* bq_word = (const float*)d_in[8];
    const float* Uc_word = (const float*)d_in[9];
    const float* v_word  = (const float*)d_in[10];
    const float* Wq_sent = (const float*)d_in[11];
    const float* bq_sent = (const float*)d_in[12];
    const float* Uc_sent = (const float*)d_in[13];
    const float* v_sent  = (const float*)d_in[14];
    const float* Wq_pass = (const float*)d_in[15];
    const float* bq_pass = (const float*)d_in[16];
    const float* Uc_pass = (const float*)d_in[17];
    const float* v_pass  = (const float*)d_in[18];

    float* wsf = (float*)d_ws;
    ushort_t* Pb = (ushort_t*)((char*)d_ws + P_BYTE_OFF);
    float* out = (float*)d_out;

    // z order: 0:Wq_word 1:Wq_sent 2:Wq_pass 3:Uc_word 4:Uc_pass 5:Uc_sent
    k1_gemm<<<dim3(8, 40, 6), dim3(256), 0, stream>>>(
        source, src_bank, qa_sent_bank, qa_word_bank,
        Wq_word, Wq_sent, Wq_pass, Uc_word, Uc_pass, Uc_sent,
        bq_word, bq_sent, bq_pass, wsf);
    k2_scores<<<dim3(NJOB_ * B_), dim3(256), 0, stream>>>(
        v_word, v_sent, v_pass, src_lengths, qa_word_lengths, wsf);
    k3a_softmax<<<dim3(200), dim3(256), 0, stream>>>(src_lengths, qa_word_lengths, wsf, Pb);
    k3c_gemm<<<dim3(16, 4), dim3(256), 0, stream>>>(Pb, src_bank, qa_word_bank, out);
}